// Round 7
// baseline (533.585 us; speedup 1.0000x reference)
//
#include <hip/hip_runtime.h>
#include <math.h>

#define BB 4
#define CC 32
#define KK 4
#define SS 4
#define NN 65536

constexpr int NCOMP = 64;       // B*K*S
constexpr int SSTRIDE = 1088;   // per-comp stats floats: Sxx[0..1023], sx[1024..1055], w[1056]
constexpr int PSTRIDE = 616;    // per-comp params: Xpacked[0..575], z[576..607], c0[608]
constexpr float EPS_ = 1e-6f;
constexpr float COVREG_ = 1e-4f;
constexpr float LOG2PI_C = 1.8378770664093453f;

// packed-triangular row offsets (row i padded to 4*(i/4+1) floats, zeros in pad)
__device__ constexpr int XOFF_[32] = {
    0,   4,   8,   12,  16,  24,  32,  40,  48,  60,  72,
    84,  96,  112, 128, 144, 160, 180, 200, 220, 240, 264,
    288, 312, 336, 364, 392, 420, 448, 480, 512, 544};

// ---------------------------------------------------------------------------
// Kernel 1: per-block partial sufficient stats.
// wave = class, 16 threads per (k,s) comp, 8x8 register tile of Sxx.
// Ballot-compacted iteration over the staged 64-element tile.
// ---------------------------------------------------------------------------
template <bool ITER0, bool ATOMIC, int TILES>
__global__ __launch_bounds__(256, 1) void gmm_accum(
    const float* __restrict__ feat, const int* __restrict__ labels,
    const float* __restrict__ resp, float* __restrict__ outbuf) {
  __shared__ float fT[64 * 36];  // [elem][channel], stride 36 (16B aligned)
  __shared__ float resp_lds[64 * 4];
  __shared__ int lab_lds[64];

  const int t = threadIdx.x;
  const int b = blockIdx.y;
  const int blk0 = blockIdx.x * (TILES * 64);

  const int wv = t >> 6;        // wave id == class
  const int l = t & 63;
  const int sc = (t >> 4) & 3;  // component s
  const int p = t & 15;
  const int a0 = (p >> 2) * 8;
  const int b0 = (p & 3) * 8;

  float acc[8][8];
#pragma unroll
  for (int x = 0; x < 8; ++x)
#pragma unroll
    for (int y = 0; y < 8; ++y) acc[x][y] = 0.f;
  float sx[8] = {0, 0, 0, 0, 0, 0, 0, 0};
  float wacc = 0.f;

  const int cload = t >> 4;     // channel 0..15 (and +16)
  const int i4 = (t & 15) * 4;  // element sub-offset

  float4 pf0, pf1;
  float4 presp = make_float4(0, 0, 0, 0);
  int plab = 0;
  // prefetch tile 0
  {
    const int n0 = blk0;
    pf0 = *(const float4*)(feat + ((size_t)b * CC + cload) * NN + n0 + i4);
    pf1 = *(const float4*)(feat + ((size_t)b * CC + cload + 16) * NN + n0 + i4);
    if (t < 64) {
      plab = labels[b * NN + n0 + t];
      if (!ITER0)
        presp = *(const float4*)(resp + ((size_t)b * NN + n0 + t) * 4);
    }
  }

  for (int tile = 0; tile < TILES; ++tile) {
    // commit prefetched tile to LDS
    fT[(i4 + 0) * 36 + cload] = pf0.x;
    fT[(i4 + 1) * 36 + cload] = pf0.y;
    fT[(i4 + 2) * 36 + cload] = pf0.z;
    fT[(i4 + 3) * 36 + cload] = pf0.w;
    fT[(i4 + 0) * 36 + cload + 16] = pf1.x;
    fT[(i4 + 1) * 36 + cload + 16] = pf1.y;
    fT[(i4 + 2) * 36 + cload + 16] = pf1.z;
    fT[(i4 + 3) * 36 + cload + 16] = pf1.w;
    if (t < 64) {
      lab_lds[t] = plab;
      if (ITER0) {
        const int cmp = (blk0 + tile * 64 + t) & 3;
        resp_lds[t * 4 + 0] = (cmp == 0) ? 1.f : 0.f;
        resp_lds[t * 4 + 1] = (cmp == 1) ? 1.f : 0.f;
        resp_lds[t * 4 + 2] = (cmp == 2) ? 1.f : 0.f;
        resp_lds[t * 4 + 3] = (cmp == 3) ? 1.f : 0.f;
      } else {
        resp_lds[t * 4 + 0] = presp.x;
        resp_lds[t * 4 + 1] = presp.y;
        resp_lds[t * 4 + 2] = presp.z;
        resp_lds[t * 4 + 3] = presp.w;
      }
    }
    __syncthreads();
    if (tile < TILES - 1) {  // prefetch next tile
      const int n0 = blk0 + (tile + 1) * 64;
      pf0 = *(const float4*)(feat + ((size_t)b * CC + cload) * NN + n0 + i4);
      pf1 =
          *(const float4*)(feat + ((size_t)b * CC + cload + 16) * NN + n0 + i4);
      if (t < 64) {
        plab = labels[b * NN + n0 + t];
        if (!ITER0)
          presp = *(const float4*)(resp + ((size_t)b * NN + n0 + t) * 4);
      }
    }

    unsigned long long m = __ballot(lab_lds[l] == wv);
    while (m) {
      const int i = __builtin_ctzll(m);
      m &= m - 1;
      const float rs = resp_lds[i * 4 + sc];
      const float4 ra0 = *(const float4*)&fT[i * 36 + a0];
      const float4 ra1 = *(const float4*)&fT[i * 36 + a0 + 4];
      const float4 rb0 = *(const float4*)&fT[i * 36 + b0];
      const float4 rb1 = *(const float4*)&fT[i * 36 + b0 + 4];
      const float ra[8] = {ra0.x, ra0.y, ra0.z, ra0.w,
                           ra1.x, ra1.y, ra1.z, ra1.w};
      const float rb[8] = {rb0.x, rb0.y, rb0.z, rb0.w,
                           rb1.x, rb1.y, rb1.z, rb1.w};
#pragma unroll
      for (int x = 0; x < 8; ++x) {
        const float v = rs * ra[x];
#pragma unroll
        for (int y = 0; y < 8; ++y) acc[x][y] = fmaf(v, rb[y], acc[x][y]);
      }
#pragma unroll
      for (int y = 0; y < 8; ++y) sx[y] = fmaf(rs, rb[y], sx[y]);
      wacc += rs;
    }
    __syncthreads();
  }

  if (ATOMIC) {
    float* sg = outbuf + ((size_t)(b * KK + wv) * SS + sc) * SSTRIDE;
#pragma unroll
    for (int x = 0; x < 8; ++x)
#pragma unroll
      for (int y = 0; y < 8; ++y)
        atomicAdd(sg + (a0 + x) * 32 + b0 + y, acc[x][y]);
    if (p < 4) {
#pragma unroll
      for (int y = 0; y < 8; ++y) atomicAdd(sg + 1024 + b0 + y, sx[y]);
    }
    if (p == 0) atomicAdd(sg + 1056, wacc);
  } else {
    const int nb = NN / (TILES * 64);
    float* sg = outbuf + ((size_t)(b * nb + blockIdx.x) * 16 + (wv * 4 + sc)) *
                             SSTRIDE;
#pragma unroll
    for (int x = 0; x < 8; ++x)
#pragma unroll
      for (int y = 0; y < 8; ++y) sg[(a0 + x) * 32 + b0 + y] = acc[x][y];
    if (p < 4) {
#pragma unroll
      for (int y = 0; y < 8; ++y) sg[1024 + b0 + y] = sx[y];
    }
    if (p == 0) sg[1056] = wacc;
  }
}

// ---------------------------------------------------------------------------
// Kernel 1b: reduce block-partials -> stats.
// One thread per (comp, cell), coalesced across the wave, ILP via 2 accums.
// ---------------------------------------------------------------------------
__global__ __launch_bounds__(256) void gmm_reduce(const float* __restrict__ part,
                                                  float* __restrict__ stats,
                                                  int nb) {
  const int idx = blockIdx.x * 256 + threadIdx.x;
  if (idx >= NCOMP * 1057) return;
  const int comp = idx / 1057;
  const int cell = idx - comp * 1057;
  const int b = comp >> 4, cl = comp & 15;
  const float* src = part + ((size_t)(b * nb) * 16 + cl) * SSTRIDE + cell;
  const size_t stride = (size_t)16 * SSTRIDE;
  float s0 = 0.f, s1 = 0.f;
#pragma unroll 8
  for (int blk = 0; blk < nb; blk += 2) {
    s0 += src[(size_t)blk * stride];
    s1 += src[(size_t)(blk + 1) * stride];
  }
  stats[(size_t)comp * SSTRIDE + cell] = s0 + s1;
}

// ---------------------------------------------------------------------------
// Kernel 2: params. cov -> Cholesky L -> X=inv(L) (packed tri), z=X*mu,
// c0 = log(pi) - 0.5*(C*log2pi + logdet).  One wave per component.
// ---------------------------------------------------------------------------
__global__ __launch_bounds__(64) void gmm_params(const float* __restrict__ stats,
                                                 float* __restrict__ params) {
  __shared__ float A[32 * 33];
  __shared__ float X[32 * 33];
  __shared__ float mu[32];

  const int t = threadIdx.x;
  const int comp = blockIdx.x;
  const float* sg = stats + (size_t)comp * SSTRIDE;

  const float w = sg[1056];
  const float invw = 1.f / (w + EPS_);
  if (t < 32) mu[t] = sg[1024 + t] * invw;
  __syncthreads();

  for (int idx = t; idx < 1024; idx += 64) {
    const int c = idx >> 5, d = idx & 31;
    float v = sg[idx] * invw - mu[c] * mu[d];
    if (c == d) v += COVREG_;
    A[c * 33 + d] = v;
  }
  __syncthreads();

  float ldet = 0.f;
  for (int j = 0; j < 32; ++j) {
    const float diag = A[j * 33 + j];
    ldet += logf(diag);
    const float ljj = sqrtf(diag);
    const float inv = 1.f / ljj;
    __syncthreads();
    if (t == 0) A[j * 33 + j] = ljj;
    if (t < 31 - j) A[(j + 1 + t) * 33 + j] *= inv;
    __syncthreads();
    if (t < 31 - j) {
      const int i = j + 1 + t;
      const float lij = A[i * 33 + j];
      for (int m = j + 1; m <= i; ++m) A[i * 33 + m] -= lij * A[m * 33 + j];
    }
    __syncthreads();
  }

  // X = inv(L), lane c handles column c
  if (t < 32) {
    const int c = t;
    for (int i = c; i < 32; ++i) {
      float sum = (i == c) ? 1.f : 0.f;
      for (int m = c; m < i; ++m) sum -= A[i * 33 + m] * X[m * 33 + c];
      X[i * 33 + c] = sum / A[i * 33 + i];
    }
  }
  __syncthreads();

  float* pg = params + (size_t)comp * PSTRIDE;
  for (int i = 0; i < 32; ++i) {
    const int L4 = 4 * ((i >> 2) + 1);
    if (t < L4) pg[XOFF_[i] + t] = (t <= i) ? X[i * 33 + t] : 0.f;
  }
  if (t < 32) {
    float z = 0.f;
    for (int j = 0; j <= t; ++j) z += X[t * 33 + j] * mu[j];
    pg[576 + t] = z;
  }
  if (t == 0) {
    const int sib = comp & ~3;
    float wsum = 0.f;
    for (int s2 = 0; s2 < 4; ++s2) wsum += stats[(size_t)(sib + s2) * SSTRIDE + 1056];
    const float pi = (w + EPS_) / (wsum + SS * EPS_);
    pg[608] = logf(pi) - 0.5f * (CC * LOG2PI_C + ldet);
  }
}

// ---------------------------------------------------------------------------
// Kernel 3a: E-step own-class -> responsibilities (R4 per-thread version).
// logp = c0 - 0.5*||X f - z||^2.  Params in LDS (label-DIVERGENT reads need
// LDS), one non-overlapping slot of SLOT floats per comp, skewed by k*4 so
// the 4 label-divergent b128 reads land on disjoint banks.
// ---------------------------------------------------------------------------
constexpr int SLOT = PSTRIDE + 16;  // 632: no overlap (gap >= 4 floats)

__global__ __launch_bounds__(256) void gmm_estep_own(
    const float* __restrict__ feat, const int* __restrict__ labels,
    const float* __restrict__ params, float* __restrict__ resp) {
  __shared__ float plds[16 * SLOT];
  const int t = threadIdx.x;
  const int b = blockIdx.y;
  const int n = blockIdx.x * 256 + t;

  // stage: comp (k,s) -> slot (s*4+k), base offset k*4 inside the slot
  for (int comp = 0; comp < 16; ++comp) {
    const int k = comp >> 2, s = comp & 3;
    const float* src = params + (size_t)(b * 16 + comp) * PSTRIDE;
    float* dst = plds + (s * 4 + k) * SLOT + k * 4;
    for (int j = t; j < PSTRIDE; j += 256) dst[j] = src[j];
  }

  float f[32];
#pragma unroll
  for (int c = 0; c < 32; ++c) f[c] = feat[((size_t)b * CC + c) * NN + n];
  const int lab = labels[b * NN + n];
  __syncthreads();

  float lp0 = 0.f, lp1 = 0.f, lp2 = 0.f, lp3 = 0.f;
#pragma unroll 1
  for (int s = 0; s < 4; ++s) {
    const float* Xp = plds + (s * 4 + lab) * SLOT + lab * 4;
    float q = 0.f;
#pragma unroll
    for (int i = 0; i < 32; ++i) {
      const int g = i >> 2;
      float y = 0.f;
#pragma unroll
      for (int j4 = 0; j4 <= g; ++j4) {
        const float4 xv = *(const float4*)(Xp + XOFF_[i] + 4 * j4);
        y = fmaf(xv.x, f[4 * j4 + 0], y);
        y = fmaf(xv.y, f[4 * j4 + 1], y);
        y = fmaf(xv.z, f[4 * j4 + 2], y);
        y = fmaf(xv.w, f[4 * j4 + 3], y);
      }
      const float d = y - Xp[576 + i];
      q = fmaf(d, d, q);
    }
    const float lp = Xp[608] - 0.5f * q;
    lp0 = (s == 0) ? lp : lp0;
    lp1 = (s == 1) ? lp : lp1;
    lp2 = (s == 2) ? lp : lp2;
    lp3 = (s == 3) ? lp : lp3;
  }
  const float m = fmaxf(fmaxf(lp0, lp1), fmaxf(lp2, lp3));
  const float e0 = expf(lp0 - m), e1 = expf(lp1 - m);
  const float e2 = expf(lp2 - m), e3 = expf(lp3 - m);
  const float inv = 1.f / (e0 + e1 + e2 + e3);
  *(float4*)(resp + ((size_t)b * NN + n) * 4) =
      make_float4(e0 * inv, e1 * inv, e2 * inv, e3 * inv);
}

// ---------------------------------------------------------------------------
// Kernel 3b: final E-step, all 16 comps, 2 elems/thread (R4 online-LSE shape)
// BUT X/z/c0 read directly from GLOBAL params at wave-UNIFORM addresses:
// the backend scalarizes these to s_load on the SMEM pipe, taking the 2304
// ds_read_b128/wave off the saturated LDS pipe (R6 diagnosis: LDS-bound,
// 27.6K LDS-cyc/wave ~ 92us floor ~ measured 99us).  No LDS, no barrier.
// ---------------------------------------------------------------------------
__global__ __launch_bounds__(256) void gmm_estep_final(
    const float* __restrict__ feat, const float* __restrict__ params,
    float* __restrict__ out) {
  const int t = threadIdx.x;
  const int b = blockIdx.y;
  const int n0 = blockIdx.x * 512 + t;

  float f0[32], f1[32];
#pragma unroll
  for (int c = 0; c < 32; ++c) {
    f0[c] = feat[((size_t)b * CC + c) * NN + n0];
    f1[c] = feat[((size_t)b * CC + c) * NN + n0 + 256];
  }

  float cA0 = 0, cA1 = 0, cA2 = 0, cA3 = 0;
  float cB0 = 0, cB1 = 0, cB2 = 0, cB3 = 0;

#pragma unroll 1
  for (int k = 0; k < 4; ++k) {
    float mA = -1e30f, sA = 0.f, mB = -1e30f, sB = 0.f;
#pragma unroll 1
    for (int s = 0; s < 4; ++s) {
      const float* Xp = params + (size_t)((b * KK + k) * SS + s) * PSTRIDE;
      float qA = 0.f, qB = 0.f;
#pragma unroll
      for (int i = 0; i < 32; ++i) {
        const int g = i >> 2;
        float yA = 0.f, yB = 0.f;
#pragma unroll
        for (int j4 = 0; j4 <= g; ++j4) {
          const float4 xv = *(const float4*)(Xp + XOFF_[i] + 4 * j4);
          yA = fmaf(xv.x, f0[4 * j4 + 0], yA);
          yA = fmaf(xv.y, f0[4 * j4 + 1], yA);
          yA = fmaf(xv.z, f0[4 * j4 + 2], yA);
          yA = fmaf(xv.w, f0[4 * j4 + 3], yA);
          yB = fmaf(xv.x, f1[4 * j4 + 0], yB);
          yB = fmaf(xv.y, f1[4 * j4 + 1], yB);
          yB = fmaf(xv.z, f1[4 * j4 + 2], yB);
          yB = fmaf(xv.w, f1[4 * j4 + 3], yB);
        }
        const float zi = Xp[576 + i];
        const float dA = yA - zi;
        qA = fmaf(dA, dA, qA);
        const float dB = yB - zi;
        qB = fmaf(dB, dB, qB);
      }
      const float c0v = Xp[608];
      const float lA = c0v - 0.5f * qA;
      const float lB = c0v - 0.5f * qB;
      const float nmA = fmaxf(mA, lA);
      sA = sA * expf(mA - nmA) + expf(lA - nmA);
      mA = nmA;
      const float nmB = fmaxf(mB, lB);
      sB = sB * expf(mB - nmB) + expf(lB - nmB);
      mB = nmB;
    }
    const float cllA = mA + logf(sA);
    const float cllB = mB + logf(sB);
    cA0 = (k == 0) ? cllA : cA0;
    cA1 = (k == 1) ? cllA : cA1;
    cA2 = (k == 2) ? cllA : cA2;
    cA3 = (k == 3) ? cllA : cA3;
    cB0 = (k == 0) ? cllB : cB0;
    cB1 = (k == 1) ? cllB : cB1;
    cB2 = (k == 2) ? cllB : cB2;
    cB3 = (k == 3) ? cllB : cB3;
  }

  {
    const float m = fmaxf(fmaxf(cA0, cA1), fmaxf(cA2, cA3));
    const float e0 = expf(cA0 - m), e1 = expf(cA1 - m);
    const float e2 = expf(cA2 - m), e3 = expf(cA3 - m);
    const float inv = 1.f / (e0 + e1 + e2 + e3);
    out[((size_t)b * KK + 0) * NN + n0] = e0 * inv;
    out[((size_t)b * KK + 1) * NN + n0] = e1 * inv;
    out[((size_t)b * KK + 2) * NN + n0] = e2 * inv;
    out[((size_t)b * KK + 3) * NN + n0] = e3 * inv;
  }
  {
    const float m = fmaxf(fmaxf(cB0, cB1), fmaxf(cB2, cB3));
    const float e0 = expf(cB0 - m), e1 = expf(cB1 - m);
    const float e2 = expf(cB2 - m), e3 = expf(cB3 - m);
    const float inv = 1.f / (e0 + e1 + e2 + e3);
    out[((size_t)b * KK + 0) * NN + n0 + 256] = e0 * inv;
    out[((size_t)b * KK + 1) * NN + n0 + 256] = e1 * inv;
    out[((size_t)b * KK + 2) * NN + n0 + 256] = e2 * inv;
    out[((size_t)b * KK + 3) * NN + n0 + 256] = e3 * inv;
  }
}

// ---------------------------------------------------------------------------
extern "C" void kernel_launch(void* const* d_in, const int* in_sizes, int n_in,
                              void* d_out, int out_size, void* d_ws,
                              size_t ws_size, hipStream_t stream) {
  const float* feat = (const float*)d_in[0];
  const int* labels = (const int*)d_in[1];
  float* out = (float*)d_out;

  float* stats = (float*)d_ws;
  float* params = stats + (size_t)NCOMP * SSTRIDE;
  float* resp_ws = params + (size_t)NCOMP * PSTRIDE;
  float* partials = resp_ws + (size_t)BB * NN * 4;

  constexpr int NB = 128;  // accum blocks per b on the partial path (TILES=8)
  const size_t resp_end_b =
      ((size_t)NCOMP * SSTRIDE + (size_t)NCOMP * PSTRIDE + (size_t)BB * NN * 4) *
      sizeof(float);
  const size_t part_end_b =
      resp_end_b + (size_t)BB * NB * 16 * SSTRIDE * sizeof(float);
  const bool have_resp = ws_size >= resp_end_b;
  const bool have_part = ws_size >= part_end_b;
  float* resp = have_resp ? resp_ws : out;

  const int reduce_blocks = (NCOMP * 1057 + 255) / 256;

  for (int it = 0; it < 3; ++it) {
    if (have_part) {
      if (it == 0)
        gmm_accum<true, false, 8>
            <<<dim3(NB, BB), 256, 0, stream>>>(feat, labels, resp, partials);
      else
        gmm_accum<false, false, 8>
            <<<dim3(NB, BB), 256, 0, stream>>>(feat, labels, resp, partials);
      gmm_reduce<<<reduce_blocks, 256, 0, stream>>>(partials, stats, NB);
    } else {
      hipMemsetAsync(stats, 0, (size_t)NCOMP * SSTRIDE * sizeof(float), stream);
      if (it == 0)
        gmm_accum<true, true, 16>
            <<<dim3(64, BB), 256, 0, stream>>>(feat, labels, resp, stats);
      else
        gmm_accum<false, true, 16>
            <<<dim3(64, BB), 256, 0, stream>>>(feat, labels, resp, stats);
    }
    gmm_params<<<NCOMP, 64, 0, stream>>>(stats, params);
    if (it < 2)
      gmm_estep_own<<<dim3(256, BB), 256, 0, stream>>>(feat, labels, params,
                                                       resp);
    else
      gmm_estep_final<<<dim3(128, BB), 256, 0, stream>>>(feat, params, out);
  }
}

// Round 9
// 484.489 us; speedup vs baseline: 1.1013x; 1.1013x over previous
//
#include <hip/hip_runtime.h>
#include <hip/hip_fp16.h>
#include <math.h>

#define BB 4
#define CC 32
#define KK 4
#define SS 4
#define NN 65536

constexpr int NCOMP = 64;      // B*K*S
constexpr int SSTRIDE = 1088;  // stats: Sxx[0..1023], sx[1024..1055], w[1056]
// params per comp: X fp32 packed [0..575], z[576..607], c0[608],
//                  X fp16 packed-8 [612..931] (320 floats = 640 halves)
constexpr int PSTRIDE = 936;
constexpr float EPS_ = 1e-6f;
constexpr float COVREG_ = 1e-4f;
constexpr float LOG2PI_C = 1.8378770664093453f;

// fp32 packed-triangular row offsets (row i padded to 4*(i/4+1) floats)
__device__ constexpr int XOFF_[32] = {
    0,   4,   8,   12,  16,  24,  32,  40,  48,  60,  72,
    84,  96,  112, 128, 144, 160, 180, 200, 220, 240, 264,
    288, 312, 336, 364, 392, 420, 448, 480, 512, 544};

// fp16 packed rows, padded to 8*(i/8+1) halves; offsets in halves
__device__ constexpr int XOFF8_[32] = {
    0,   8,   16,  24,  32,  40,  48,  56,  64,  80,  96,
    112, 128, 144, 160, 176, 192, 216, 240, 264, 288, 312,
    336, 360, 384, 416, 448, 480, 512, 544, 576, 608};

// ---------------------------------------------------------------------------
// Kernel 1: per-block partial sufficient stats (unchanged from R4).
// ---------------------------------------------------------------------------
template <bool ITER0, bool ATOMIC, int TILES>
__global__ __launch_bounds__(256, 1) void gmm_accum(
    const float* __restrict__ feat, const int* __restrict__ labels,
    const float* __restrict__ resp, float* __restrict__ outbuf) {
  __shared__ float fT[64 * 36];
  __shared__ float resp_lds[64 * 4];
  __shared__ int lab_lds[64];

  const int t = threadIdx.x;
  const int b = blockIdx.y;
  const int blk0 = blockIdx.x * (TILES * 64);

  const int wv = t >> 6;
  const int l = t & 63;
  const int sc = (t >> 4) & 3;
  const int p = t & 15;
  const int a0 = (p >> 2) * 8;
  const int b0 = (p & 3) * 8;

  float acc[8][8];
#pragma unroll
  for (int x = 0; x < 8; ++x)
#pragma unroll
    for (int y = 0; y < 8; ++y) acc[x][y] = 0.f;
  float sx[8] = {0, 0, 0, 0, 0, 0, 0, 0};
  float wacc = 0.f;

  const int cload = t >> 4;
  const int i4 = (t & 15) * 4;

  float4 pf0, pf1;
  float4 presp = make_float4(0, 0, 0, 0);
  int plab = 0;
  {
    const int n0 = blk0;
    pf0 = *(const float4*)(feat + ((size_t)b * CC + cload) * NN + n0 + i4);
    pf1 = *(const float4*)(feat + ((size_t)b * CC + cload + 16) * NN + n0 + i4);
    if (t < 64) {
      plab = labels[b * NN + n0 + t];
      if (!ITER0)
        presp = *(const float4*)(resp + ((size_t)b * NN + n0 + t) * 4);
    }
  }

  for (int tile = 0; tile < TILES; ++tile) {
    fT[(i4 + 0) * 36 + cload] = pf0.x;
    fT[(i4 + 1) * 36 + cload] = pf0.y;
    fT[(i4 + 2) * 36 + cload] = pf0.z;
    fT[(i4 + 3) * 36 + cload] = pf0.w;
    fT[(i4 + 0) * 36 + cload + 16] = pf1.x;
    fT[(i4 + 1) * 36 + cload + 16] = pf1.y;
    fT[(i4 + 2) * 36 + cload + 16] = pf1.z;
    fT[(i4 + 3) * 36 + cload + 16] = pf1.w;
    if (t < 64) {
      lab_lds[t] = plab;
      if (ITER0) {
        const int cmp = (blk0 + tile * 64 + t) & 3;
        resp_lds[t * 4 + 0] = (cmp == 0) ? 1.f : 0.f;
        resp_lds[t * 4 + 1] = (cmp == 1) ? 1.f : 0.f;
        resp_lds[t * 4 + 2] = (cmp == 2) ? 1.f : 0.f;
        resp_lds[t * 4 + 3] = (cmp == 3) ? 1.f : 0.f;
      } else {
        resp_lds[t * 4 + 0] = presp.x;
        resp_lds[t * 4 + 1] = presp.y;
        resp_lds[t * 4 + 2] = presp.z;
        resp_lds[t * 4 + 3] = presp.w;
      }
    }
    __syncthreads();
    if (tile < TILES - 1) {
      const int n0 = blk0 + (tile + 1) * 64;
      pf0 = *(const float4*)(feat + ((size_t)b * CC + cload) * NN + n0 + i4);
      pf1 =
          *(const float4*)(feat + ((size_t)b * CC + cload + 16) * NN + n0 + i4);
      if (t < 64) {
        plab = labels[b * NN + n0 + t];
        if (!ITER0)
          presp = *(const float4*)(resp + ((size_t)b * NN + n0 + t) * 4);
      }
    }

    unsigned long long m = __ballot(lab_lds[l] == wv);
    while (m) {
      const int i = __builtin_ctzll(m);
      m &= m - 1;
      const float rs = resp_lds[i * 4 + sc];
      const float4 ra0 = *(const float4*)&fT[i * 36 + a0];
      const float4 ra1 = *(const float4*)&fT[i * 36 + a0 + 4];
      const float4 rb0 = *(const float4*)&fT[i * 36 + b0];
      const float4 rb1 = *(const float4*)&fT[i * 36 + b0 + 4];
      const float ra[8] = {ra0.x, ra0.y, ra0.z, ra0.w,
                           ra1.x, ra1.y, ra1.z, ra1.w};
      const float rb[8] = {rb0.x, rb0.y, rb0.z, rb0.w,
                           rb1.x, rb1.y, rb1.z, rb1.w};
#pragma unroll
      for (int x = 0; x < 8; ++x) {
        const float v = rs * ra[x];
#pragma unroll
        for (int y = 0; y < 8; ++y) acc[x][y] = fmaf(v, rb[y], acc[x][y]);
      }
#pragma unroll
      for (int y = 0; y < 8; ++y) sx[y] = fmaf(rs, rb[y], sx[y]);
      wacc += rs;
    }
    __syncthreads();
  }

  if (ATOMIC) {
    float* sg = outbuf + ((size_t)(b * KK + wv) * SS + sc) * SSTRIDE;
#pragma unroll
    for (int x = 0; x < 8; ++x)
#pragma unroll
      for (int y = 0; y < 8; ++y)
        atomicAdd(sg + (a0 + x) * 32 + b0 + y, acc[x][y]);
    if (p < 4) {
#pragma unroll
      for (int y = 0; y < 8; ++y) atomicAdd(sg + 1024 + b0 + y, sx[y]);
    }
    if (p == 0) atomicAdd(sg + 1056, wacc);
  } else {
    const int nb = NN / (TILES * 64);
    float* sg = outbuf + ((size_t)(b * nb + blockIdx.x) * 16 + (wv * 4 + sc)) *
                             SSTRIDE;
#pragma unroll
    for (int x = 0; x < 8; ++x)
#pragma unroll
      for (int y = 0; y < 8; ++y) sg[(a0 + x) * 32 + b0 + y] = acc[x][y];
    if (p < 4) {
#pragma unroll
      for (int y = 0; y < 8; ++y) sg[1024 + b0 + y] = sx[y];
    }
    if (p == 0) sg[1056] = wacc;
  }
}

// ---------------------------------------------------------------------------
// Kernel 1b: reduce block-partials -> stats (unchanged).
// ---------------------------------------------------------------------------
__global__ __launch_bounds__(256) void gmm_reduce(const float* __restrict__ part,
                                                  float* __restrict__ stats,
                                                  int nb) {
  const int idx = blockIdx.x * 256 + threadIdx.x;
  if (idx >= NCOMP * 1057) return;
  const int comp = idx / 1057;
  const int cell = idx - comp * 1057;
  const int b = comp >> 4, cl = comp & 15;
  const float* src = part + ((size_t)(b * nb) * 16 + cl) * SSTRIDE + cell;
  const size_t stride = (size_t)16 * SSTRIDE;
  float s0 = 0.f, s1 = 0.f;
#pragma unroll 8
  for (int blk = 0; blk < nb; blk += 2) {
    s0 += src[(size_t)blk * stride];
    s1 += src[(size_t)(blk + 1) * stride];
  }
  stats[(size_t)comp * SSTRIDE + cell] = s0 + s1;
}

// ---------------------------------------------------------------------------
// Kernel 2: params.  Emits fp32 packed X, z, c0, and packed fp16 X.
// ---------------------------------------------------------------------------
__global__ __launch_bounds__(64) void gmm_params(const float* __restrict__ stats,
                                                 float* __restrict__ params) {
  __shared__ float A[32 * 33];
  __shared__ float X[32 * 33];
  __shared__ float mu[32];

  const int t = threadIdx.x;
  const int comp = blockIdx.x;
  const float* sg = stats + (size_t)comp * SSTRIDE;

  const float w = sg[1056];
  const float invw = 1.f / (w + EPS_);
  if (t < 32) mu[t] = sg[1024 + t] * invw;
  __syncthreads();

  for (int idx = t; idx < 1024; idx += 64) {
    const int c = idx >> 5, d = idx & 31;
    float v = sg[idx] * invw - mu[c] * mu[d];
    if (c == d) v += COVREG_;
    A[c * 33 + d] = v;
  }
  __syncthreads();

  float ldet = 0.f;
  for (int j = 0; j < 32; ++j) {
    const float diag = A[j * 33 + j];
    ldet += logf(diag);
    const float ljj = sqrtf(diag);
    const float inv = 1.f / ljj;
    __syncthreads();
    if (t == 0) A[j * 33 + j] = ljj;
    if (t < 31 - j) A[(j + 1 + t) * 33 + j] *= inv;
    __syncthreads();
    if (t < 31 - j) {
      const int i = j + 1 + t;
      const float lij = A[i * 33 + j];
      for (int m = j + 1; m <= i; ++m) A[i * 33 + m] -= lij * A[m * 33 + j];
    }
    __syncthreads();
  }

  if (t < 32) {
    const int c = t;
    for (int i = c; i < 32; ++i) {
      float sum = (i == c) ? 1.f : 0.f;
      for (int m = c; m < i; ++m) sum -= A[i * 33 + m] * X[m * 33 + c];
      X[i * 33 + c] = sum / A[i * 33 + i];
    }
  }
  __syncthreads();

  float* pg = params + (size_t)comp * PSTRIDE;
  for (int i = 0; i < 32; ++i) {
    const int L4 = 4 * ((i >> 2) + 1);
    if (t < L4) pg[XOFF_[i] + t] = (t <= i) ? X[i * 33 + t] : 0.f;
  }
  // fp16 packed copy (8-half chunks per row)
  {
    __half* xh = (__half*)(pg + 612);
    for (int i = 0; i < 32; ++i) {
      const int nh = 8 * ((i >> 3) + 1);
      if (t < nh) {
        const float v = (t <= i) ? X[i * 33 + t] : 0.f;
        xh[XOFF8_[i] + t] = __float2half(v);
      }
    }
  }
  if (t < 32) {
    float z = 0.f;
    for (int j = 0; j <= t; ++j) z += X[t * 33 + j] * mu[j];
    pg[576 + t] = z;
  }
  if (t == 0) {
    const int sib = comp & ~3;
    float wsum = 0.f;
    for (int s2 = 0; s2 < 4; ++s2)
      wsum += stats[(size_t)(sib + s2) * SSTRIDE + 1056];
    const float pi = (w + EPS_) / (wsum + SS * EPS_);
    pg[608] = logf(pi) - 0.5f * (CC * LOG2PI_C + ldet);
  }
}

// ---------------------------------------------------------------------------
// Kernel 3a v3: E-step own-class, per-thread (R4 structure) with fp16 X.
// Slot layout (floats): Xh[0..319] (=640 halves), z[320..351], c0[352].
// SLOT2=368 >= payload(353)+max skew(12): NO inter-slot overlap (R8 bug).
// Slot stride 368 -> bank shift 16/slot; comp (k,s) -> slot (s*4+k) skewed
// by k*4 floats => label group k reads at bank 20k mod 32 = {0,20,8,28}:
// disjoint quartets for the 4 divergent 16B reads.
// ---------------------------------------------------------------------------
constexpr int SLOT2 = 368;

__global__ __launch_bounds__(256) void gmm_estep_own(
    const float* __restrict__ feat, const int* __restrict__ labels,
    const float* __restrict__ params, float* __restrict__ resp) {
  __shared__ float plds[16 * SLOT2];
  const int t = threadIdx.x;
  const int b = blockIdx.y;
  const int n = blockIdx.x * 256 + t;

  // stage: Xh floats from pg[612..932), z from pg[576..608), c0 pg[608]
  for (int comp = 0; comp < 16; ++comp) {
    const int k = comp >> 2, s = comp & 3;
    const float* src = params + (size_t)(b * 16 + comp) * PSTRIDE;
    float* dst = plds + (s * 4 + k) * SLOT2 + k * 4;
    for (int j = t; j < 353; j += 256) {
      float v;
      if (j < 320)
        v = src[612 + j];
      else if (j < 352)
        v = src[576 + (j - 320)];
      else
        v = src[608];
      dst[j] = v;
    }
  }

  float f[32];
#pragma unroll
  for (int c = 0; c < 32; ++c) f[c] = feat[((size_t)b * CC + c) * NN + n];
  const int lab = labels[b * NN + n];
  __syncthreads();

  float lp0 = 0.f, lp1 = 0.f, lp2 = 0.f, lp3 = 0.f;
#pragma unroll 1
  for (int s = 0; s < 4; ++s) {
    const float* Xp = plds + (s * 4 + lab) * SLOT2 + lab * 4;
    const __half* Xh = (const __half*)Xp;
    float q = 0.f;
#pragma unroll
    for (int i4g = 0; i4g < 8; ++i4g) {
      const float4 zv = *(const float4*)(Xp + 320 + 4 * i4g);
      const float zarr[4] = {zv.x, zv.y, zv.z, zv.w};
#pragma unroll
      for (int ii = 0; ii < 4; ++ii) {
        const int i = 4 * i4g + ii;
        float y = 0.f;
#pragma unroll
        for (int j8 = 0; j8 <= (i >> 3); ++j8) {
          const int4 ch = *(const int4*)(Xh + XOFF8_[i] + 8 * j8);
          const __half2 h0 = __builtin_bit_cast(__half2, ch.x);
          const __half2 h1 = __builtin_bit_cast(__half2, ch.y);
          const __half2 h2 = __builtin_bit_cast(__half2, ch.z);
          const __half2 h3 = __builtin_bit_cast(__half2, ch.w);
          y = fmaf(__low2float(h0), f[8 * j8 + 0], y);
          y = fmaf(__high2float(h0), f[8 * j8 + 1], y);
          y = fmaf(__low2float(h1), f[8 * j8 + 2], y);
          y = fmaf(__high2float(h1), f[8 * j8 + 3], y);
          y = fmaf(__low2float(h2), f[8 * j8 + 4], y);
          y = fmaf(__high2float(h2), f[8 * j8 + 5], y);
          y = fmaf(__low2float(h3), f[8 * j8 + 6], y);
          y = fmaf(__high2float(h3), f[8 * j8 + 7], y);
        }
        const float d = y - zarr[ii];
        q = fmaf(d, d, q);
      }
    }
    const float lp = Xp[352] - 0.5f * q;
    lp0 = (s == 0) ? lp : lp0;
    lp1 = (s == 1) ? lp : lp1;
    lp2 = (s == 2) ? lp : lp2;
    lp3 = (s == 3) ? lp : lp3;
  }
  const float m = fmaxf(fmaxf(lp0, lp1), fmaxf(lp2, lp3));
  const float e0 = expf(lp0 - m), e1 = expf(lp1 - m);
  const float e2 = expf(lp2 - m), e3 = expf(lp3 - m);
  const float inv = 1.f / (e0 + e1 + e2 + e3);
  *(float4*)(resp + ((size_t)b * NN + n) * 4) =
      make_float4(e0 * inv, e1 * inv, e2 * inv, e3 * inv);
}

// ---------------------------------------------------------------------------
// Kernel 3b: final E-step — R4-exact structure (LDS-staged fp32 X, online
// LSE, 2 elems/thread; measured best at 99us).  Local LDS stride 616.
// ---------------------------------------------------------------------------
__global__ __launch_bounds__(256, 2) void gmm_estep_final(
    const float* __restrict__ feat, const float* __restrict__ params,
    float* __restrict__ out) {
  __shared__ float plds[16 * 616];
  const int t = threadIdx.x;
  const int b = blockIdx.y;
  const int n0 = blockIdx.x * 512 + t;

  for (int comp = 0; comp < 16; ++comp) {
    const float* src = params + (size_t)(b * 16 + comp) * PSTRIDE;
    float* dst = plds + comp * 616;
    for (int j = t; j < 609; j += 256) dst[j] = src[j];
  }

  float f0[32], f1[32];
#pragma unroll
  for (int c = 0; c < 32; ++c) {
    f0[c] = feat[((size_t)b * CC + c) * NN + n0];
    f1[c] = feat[((size_t)b * CC + c) * NN + n0 + 256];
  }
  __syncthreads();

  float cA0 = 0, cA1 = 0, cA2 = 0, cA3 = 0;
  float cB0 = 0, cB1 = 0, cB2 = 0, cB3 = 0;

#pragma unroll 1
  for (int k = 0; k < 4; ++k) {
    float mA = -1e30f, sA = 0.f, mB = -1e30f, sB = 0.f;
#pragma unroll 1
    for (int s = 0; s < 4; ++s) {
      const float* Xp = plds + (k * 4 + s) * 616;
      float qA = 0.f, qB = 0.f;
#pragma unroll
      for (int i = 0; i < 32; ++i) {
        const int g = i >> 2;
        float yA = 0.f, yB = 0.f;
#pragma unroll
        for (int j4 = 0; j4 <= g; ++j4) {
          const float4 xv = *(const float4*)(Xp + XOFF_[i] + 4 * j4);
          yA = fmaf(xv.x, f0[4 * j4 + 0], yA);
          yA = fmaf(xv.y, f0[4 * j4 + 1], yA);
          yA = fmaf(xv.z, f0[4 * j4 + 2], yA);
          yA = fmaf(xv.w, f0[4 * j4 + 3], yA);
          yB = fmaf(xv.x, f1[4 * j4 + 0], yB);
          yB = fmaf(xv.y, f1[4 * j4 + 1], yB);
          yB = fmaf(xv.z, f1[4 * j4 + 2], yB);
          yB = fmaf(xv.w, f1[4 * j4 + 3], yB);
        }
        const float zi = Xp[576 + i];
        const float dA = yA - zi;
        qA = fmaf(dA, dA, qA);
        const float dB = yB - zi;
        qB = fmaf(dB, dB, qB);
      }
      const float c0v = Xp[608];
      const float lA = c0v - 0.5f * qA;
      const float lB = c0v - 0.5f * qB;
      const float nmA = fmaxf(mA, lA);
      sA = sA * expf(mA - nmA) + expf(lA - nmA);
      mA = nmA;
      const float nmB = fmaxf(mB, lB);
      sB = sB * expf(mB - nmB) + expf(lB - nmB);
      mB = nmB;
    }
    const float cllA = mA + logf(sA);
    const float cllB = mB + logf(sB);
    cA0 = (k == 0) ? cllA : cA0;
    cA1 = (k == 1) ? cllA : cA1;
    cA2 = (k == 2) ? cllA : cA2;
    cA3 = (k == 3) ? cllA : cA3;
    cB0 = (k == 0) ? cllB : cB0;
    cB1 = (k == 1) ? cllB : cB1;
    cB2 = (k == 2) ? cllB : cB2;
    cB3 = (k == 3) ? cllB : cB3;
  }

  {
    const float m = fmaxf(fmaxf(cA0, cA1), fmaxf(cA2, cA3));
    const float e0 = expf(cA0 - m), e1 = expf(cA1 - m);
    const float e2 = expf(cA2 - m), e3 = expf(cA3 - m);
    const float inv = 1.f / (e0 + e1 + e2 + e3);
    out[((size_t)b * KK + 0) * NN + n0] = e0 * inv;
    out[((size_t)b * KK + 1) * NN + n0] = e1 * inv;
    out[((size_t)b * KK + 2) * NN + n0] = e2 * inv;
    out[((size_t)b * KK + 3) * NN + n0] = e3 * inv;
  }
  {
    const float m = fmaxf(fmaxf(cB0, cB1), fmaxf(cB2, cB3));
    const float e0 = expf(cB0 - m), e1 = expf(cB1 - m);
    const float e2 = expf(cB2 - m), e3 = expf(cB3 - m);
    const float inv = 1.f / (e0 + e1 + e2 + e3);
    out[((size_t)b * KK + 0) * NN + n0 + 256] = e0 * inv;
    out[((size_t)b * KK + 1) * NN + n0 + 256] = e1 * inv;
    out[((size_t)b * KK + 2) * NN + n0 + 256] = e2 * inv;
    out[((size_t)b * KK + 3) * NN + n0 + 256] = e3 * inv;
  }
}

// ---------------------------------------------------------------------------
extern "C" void kernel_launch(void* const* d_in, const int* in_sizes, int n_in,
                              void* d_out, int out_size, void* d_ws,
                              size_t ws_size, hipStream_t stream) {
  const float* feat = (const float*)d_in[0];
  const int* labels = (const int*)d_in[1];
  float* out = (float*)d_out;

  float* stats = (float*)d_ws;
  float* params = stats + (size_t)NCOMP * SSTRIDE;
  float* resp_ws = params + (size_t)NCOMP * PSTRIDE;
  float* partials = resp_ws + (size_t)BB * NN * 4;

  constexpr int NB = 128;
  const size_t resp_end_b =
      ((size_t)NCOMP * SSTRIDE + (size_t)NCOMP * PSTRIDE + (size_t)BB * NN * 4) *
      sizeof(float);
  const size_t part_end_b =
      resp_end_b + (size_t)BB * NB * 16 * SSTRIDE * sizeof(float);
  const bool have_resp = ws_size >= resp_end_b;
  const bool have_part = ws_size >= part_end_b;
  float* resp = have_resp ? resp_ws : out;

  const int reduce_blocks = (NCOMP * 1057 + 255) / 256;

  for (int it = 0; it < 3; ++it) {
    if (have_part) {
      if (it == 0)
        gmm_accum<true, false, 8>
            <<<dim3(NB, BB), 256, 0, stream>>>(feat, labels, resp, partials);
      else
        gmm_accum<false, false, 8>
            <<<dim3(NB, BB), 256, 0, stream>>>(feat, labels, resp, partials);
      gmm_reduce<<<reduce_blocks, 256, 0, stream>>>(partials, stats, NB);
    } else {
      hipMemsetAsync(stats, 0, (size_t)NCOMP * SSTRIDE * sizeof(float), stream);
      if (it == 0)
        gmm_accum<true, true, 16>
            <<<dim3(64, BB), 256, 0, stream>>>(feat, labels, resp, stats);
      else
        gmm_accum<false, true, 16>
            <<<dim3(64, BB), 256, 0, stream>>>(feat, labels, resp, stats);
    }
    gmm_params<<<NCOMP, 64, 0, stream>>>(stats, params);
    if (it < 2)
      gmm_estep_own<<<dim3(256, BB), 256, 0, stream>>>(feat, labels, params,
                                                       resp);
    else
      gmm_estep_final<<<dim3(128, BB), 256, 0, stream>>>(feat, params, out);
  }
}